// Round 4
// baseline (493.886 us; speedup 1.0000x reference)
//
#include <hip/hip_runtime.h>

// Problem constants (B,S,D,H from reference)
#define B_ 2
#define S_ 2048
#define D_ 1024
#define H_ 16
#define DK_ 64
#define M_ (B_ * S_)      // 4096 rows in the projection GEMMs

typedef __bf16 bf16;
typedef __attribute__((ext_vector_type(8))) __bf16 bf16x8;
typedef __attribute__((ext_vector_type(4))) __bf16 bf16x4;
typedef __attribute__((ext_vector_type(4))) float f32x4;

static __device__ __forceinline__ bf16x8 ld8(const bf16* p) {
    return *(const bf16x8*)p;   // 16B aligned by construction
}

// ---------------------------------------------------------------------------
// Elementwise fp32 -> bf16 for the 3 X inputs (into d_out scratch) and the
// 4 weight matrices (into ws). Block mapping: 3*2048 X-blocks + 4*512 W-blocks.
// ---------------------------------------------------------------------------
__global__ __launch_bounds__(256)
void cvt_all(const float* __restrict__ xq, const float* __restrict__ xk,
             const float* __restrict__ xv, const float* __restrict__ wq,
             const float* __restrict__ wk, const float* __restrict__ wv,
             const float* __restrict__ wo, bf16* __restrict__ xqo,
             bf16* __restrict__ xko, bf16* __restrict__ xvo,
             bf16* __restrict__ wqo, bf16* __restrict__ wko,
             bf16* __restrict__ wvo, bf16* __restrict__ woo)
{
    const int bx = blockIdx.x;
    const float* s; bf16* d; size_t base;
    if (bx < 6144) {
        int a = bx >> 11;
        s = (a == 0) ? xq : (a == 1) ? xk : xv;
        d = (a == 0) ? xqo : (a == 1) ? xko : xvo;
        base = (size_t)(bx & 2047) * 2048;
    } else {
        int a = (bx - 6144) >> 9;
        s = (a == 0) ? wq : (a == 1) ? wk : (a == 2) ? wv : wo;
        d = (a == 0) ? wqo : (a == 1) ? wko : (a == 2) ? wvo : woo;
        base = (size_t)((bx - 6144) & 511) * 2048;
    }
    size_t i = base + (size_t)threadIdx.x * 8;
    f32x4 a4 = *(const f32x4*)(s + i);
    f32x4 b4 = *(const f32x4*)(s + i + 4);
    bf16x8 r;
    r[0]=(bf16)a4[0]; r[1]=(bf16)a4[1]; r[2]=(bf16)a4[2]; r[3]=(bf16)a4[3];
    r[4]=(bf16)b4[0]; r[5]=(bf16)b4[1]; r[6]=(bf16)b4[2]; r[7]=(bf16)b4[3];
    *(bf16x8*)(d + i) = r;
}

// ---------------------------------------------------------------------------
// 128x128-tile bf16 GEMM, LDS-staged, 2-barrier K-loop.
// out_mode: 0 = bf16 head-split (B,H,S,DK);  1 = fp32 flat (M,N);
//           2 = bf16 TRANSPOSED head-split (B,H,DK,S)  [for V^T]
// a_headsplit: A element (m,k) at ((b*H+h)*S+s)*DK+dk (ctx layout).
// scale: applied after bias. Q gemm folds 0.125*log2(e) (softmax 1/sqrt(DK)
//        plus the exp->exp2 conversion factor).
// ---------------------------------------------------------------------------
__global__ __launch_bounds__(256)
void gemm128(const bf16* __restrict__ A, const bf16* __restrict__ W,
             const float* __restrict__ bias, void* __restrict__ out,
             int a_headsplit, int out_mode, float scale)
{
    const int m0 = blockIdx.x * 128, n0 = blockIdx.y * 128;
    const int tid = threadIdx.x;
    const int wv = tid >> 6, lane = tid & 63, quad = lane >> 4, l16 = lane & 15;
    const int wr = (wv >> 1) * 64, wc = (wv & 1) * 64;

    __shared__ bf16 As[128 * 32];
    __shared__ bf16 Bs[128 * 32];

    f32x4 acc[4][4];
#pragma unroll
    for (int i = 0; i < 4; ++i)
#pragma unroll
        for (int j = 0; j < 4; ++j) acc[i][j] = f32x4{0.f, 0.f, 0.f, 0.f};

    const int srow = tid >> 2;
    const int scol = (tid & 3) * 8;

    for (int k0 = 0; k0 < D_; k0 += 32) {
        bf16x8 av[2], bw[2];
#pragma unroll
        for (int c = 0; c < 2; ++c) {
            const int row = c * 64 + srow;
            const int k   = k0 + scol;
            const bf16* ap;
            if (a_headsplit) {
                int m = m0 + row, bb = m >> 11, ss = m & (S_ - 1);
                int hh = k >> 6, dd = k & (DK_ - 1);
                ap = A + (((size_t)(bb * H_ + hh) * S_ + ss) * DK_ + dd);
            } else {
                ap = A + (size_t)(m0 + row) * D_ + k;
            }
            av[c] = ld8(ap);
            bw[c] = ld8(W + (size_t)(n0 + row) * D_ + k);
        }
        __syncthreads();
#pragma unroll
        for (int c = 0; c < 2; ++c) {
            const int e = c * 2048 + tid * 8;
            *(bf16x8*)(As + e) = av[c];
            *(bf16x8*)(Bs + e) = bw[c];
        }
        __syncthreads();

        bf16x8 af[4], bfr[4];
#pragma unroll
        for (int i = 0; i < 4; ++i)
            af[i] = *(const bf16x8*)(As + (wr + i*16 + l16) * 32 + quad * 8);
#pragma unroll
        for (int j = 0; j < 4; ++j)
            bfr[j] = *(const bf16x8*)(Bs + (wc + j*16 + l16) * 32 + quad * 8);
#pragma unroll
        for (int i = 0; i < 4; ++i)
#pragma unroll
            for (int j = 0; j < 4; ++j)
                acc[i][j] = __builtin_amdgcn_mfma_f32_16x16x32_bf16(
                    af[i], bfr[j], acc[i][j], 0, 0, 0);
    }

#pragma unroll
    for (int i = 0; i < 4; ++i)
#pragma unroll
        for (int j = 0; j < 4; ++j) {
            const int nn = n0 + wc + j*16 + l16;
            const float bvv = bias[nn];
            const int mm0 = m0 + wr + i*16 + quad*4;   // 4-aligned, same b
            if (out_mode == 2) {
                // V^T: (B,H,DK,S); 4 consecutive tokens -> one 8B store
                bf16x4 pk;
#pragma unroll
                for (int r = 0; r < 4; ++r)
                    pk[r] = (bf16)((acc[i][j][r] + bvv) * scale);
                int bb = mm0 >> 11, ss = mm0 & (S_ - 1);
                int hh = nn >> 6,  dd = nn & (DK_ - 1);
                *(bf16x4*)((bf16*)out +
                    ((size_t)(bb * H_ + hh) * DK_ + dd) * S_ + ss) = pk;
            } else {
#pragma unroll
                for (int r = 0; r < 4; ++r) {
                    const int mm = mm0 + r;
                    float v = (acc[i][j][r] + bvv) * scale;
                    if (out_mode == 1) {
                        ((float*)out)[(size_t)mm * D_ + nn] = v;
                    } else {
                        int bb = mm >> 11, ss = mm & (S_ - 1);
                        int hh = nn >> 6, dd = nn & (DK_ - 1);
                        ((bf16*)out)[((size_t)(bb * H_ + hh) * S_ + ss) * DK_ + dd] = (bf16)v;
                    }
                }
            }
        }
}

// ---------------------------------------------------------------------------
// Context + softmax denominators, fused. 32-q-row blocks (2048 total), XCD-
// swizzled so each XCD owns 4 complete (h,b) groups -> K/V L2-resident.
// Small per-wave state (cacc 32 + qf 16 + K 16 + va 16 regs) under
// __launch_bounds__(256,4) -> 4 waves/SIMD to hide the QK->exp->PV chain
// (round-3 post-mortem: 172 regs -> 2 waves/SIMD -> 53% no-issue cycles).
// Swapped QK^T: s = mfma(K,Q) puts P[j = quad*4+r][q = l16] in registers.
// PV uses mfma_f32_16x16x32_bf16 with a CUSTOM k->j bijection
//   k = quad*8 + t*4 + r  <->  j = t*16 + quad*4 + r     (t = j-tile 0/1)
// (legal: MFMA K-dim is a pure sum) matching the P register layout exactly,
// so no P transpose / LDS staging. Scores arrive pre-scaled by 0.125*log2e
// (folded into Q projection) -> exp is a bare v_exp_f32. P~ UNNORMALIZED;
// row-sums L accumulated alongside; normalized once in epilogue. Writes Li.
// ---------------------------------------------------------------------------
__global__ __launch_bounds__(256, 4)
void attn_ctx(const bf16* __restrict__ Q, const bf16* __restrict__ K,
              const bf16* __restrict__ Vt, float* __restrict__ Li,
              bf16* __restrict__ ctxOut)
{
    // 2048 blocks; bid%8 = XCD; each XCD gets 256 consecutive semantic idx
    // = 4 full (h,b) groups (64 q-tiles of 32 rows each). Bijective.
    const int bid = blockIdx.x;
    const int l   = (bid & 7) * 256 + (bid >> 3);
    const int q0  = (l & 63) * 32;
    const int h   = (l >> 6) & 15;
    const int b   = l >> 10;

    const int tid = threadIdx.x;
    const int wv = tid >> 6, lane = tid & 63, quad = lane >> 4, l16 = lane & 15;

    __shared__ float ctxp[4][64 * 17 + 16];   // [wv][dk*17+q]  17.7 KB
    __shared__ float wp[4][2][16];            // per-wave L partials
    __shared__ float linvs[2][16];            // 1/L per (qt, q)

    const size_t hb = (size_t)(b * H_ + h) * S_;
    bf16x8 qf[2][2];
#pragma unroll
    for (int qt = 0; qt < 2; ++qt) {
        const bf16* qrow = Q + (hb + q0 + qt*16 + l16) * DK_;
        qf[qt][0] = ld8(qrow + quad*8);
        qf[qt][1] = ld8(qrow + 32 + quad*8);
    }
    const bf16* Kb  = K  + hb * DK_;
    const bf16* Vtb = Vt + hb * DK_;   // (B,H,DK,S): row d at Vtb + d*S

    f32x4 cacc[4][2];   // [db][qt]  C[dk = db*16+quad*4+r][q = l16]
#pragma unroll
    for (int db = 0; db < 4; ++db)
#pragma unroll
        for (int qt = 0; qt < 2; ++qt) cacc[db][qt] = f32x4{0.f,0.f,0.f,0.f};
    float lsum[2] = {0.f, 0.f};

    const int jbase = wv * 512;
    for (int jc = 0; jc < 16; ++jc) {
        const int j0 = jbase + jc * 32;
        const bf16* kr0 = Kb + (size_t)(j0 + l16) * DK_ + quad*8;
        const bf16* kr1 = Kb + (size_t)(j0 + 16 + l16) * DK_ + quad*8;
        bf16x8 kf0a = ld8(kr0), kf0b = ld8(kr0 + 32);
        bf16x8 kf1a = ld8(kr1), kf1b = ld8(kr1 + 32);
        // V loads issued early: independent of QK/exp, consumed by PV below
        bf16x8 va[4];
#pragma unroll
        for (int db = 0; db < 4; ++db) {
            const bf16* vr = Vtb + (size_t)(db*16 + l16) * S_ + j0 + quad*4;
            bf16x4 vlo = *(const bf16x4*)vr;         // j = j0 + quad*4 + 0..3
            bf16x4 vhi = *(const bf16x4*)(vr + 16);  // j = j0+16 + quad*4+0..3
            va[db] = __builtin_shufflevector(vlo, vhi, 0,1,2,3,4,5,6,7);
        }

        bf16x8 pa[2];
#pragma unroll
        for (int qt = 0; qt < 2; ++qt) {
            f32x4 z0 = {0.f,0.f,0.f,0.f}, z1 = {0.f,0.f,0.f,0.f};
            z0 = __builtin_amdgcn_mfma_f32_16x16x32_bf16(kf0a, qf[qt][0], z0, 0, 0, 0);
            f32x4 s0 = __builtin_amdgcn_mfma_f32_16x16x32_bf16(kf0b, qf[qt][1], z0, 0, 0, 0);
            z1 = __builtin_amdgcn_mfma_f32_16x16x32_bf16(kf1a, qf[qt][0], z1, 0, 0, 0);
            f32x4 s1 = __builtin_amdgcn_mfma_f32_16x16x32_bf16(kf1b, qf[qt][1], z1, 0, 0, 0);
            // scores pre-scaled by 0.125*log2e -> bare hardware exp2
            float e0 = __builtin_amdgcn_exp2f(fminf(s0[0], 86.f));
            float e1 = __builtin_amdgcn_exp2f(fminf(s0[1], 86.f));
            float e2 = __builtin_amdgcn_exp2f(fminf(s0[2], 86.f));
            float e3 = __builtin_amdgcn_exp2f(fminf(s0[3], 86.f));
            float e4 = __builtin_amdgcn_exp2f(fminf(s1[0], 86.f));
            float e5 = __builtin_amdgcn_exp2f(fminf(s1[1], 86.f));
            float e6 = __builtin_amdgcn_exp2f(fminf(s1[2], 86.f));
            float e7 = __builtin_amdgcn_exp2f(fminf(s1[3], 86.f));
            lsum[qt] += ((e0 + e1) + (e2 + e3)) + ((e4 + e5) + (e6 + e7));
            bf16x8 p;
            p[0]=(bf16)e0; p[1]=(bf16)e1; p[2]=(bf16)e2; p[3]=(bf16)e3;
            p[4]=(bf16)e4; p[5]=(bf16)e5; p[6]=(bf16)e6; p[7]=(bf16)e7;
            pa[qt] = p;
        }
#pragma unroll
        for (int db = 0; db < 4; ++db)
#pragma unroll
            for (int qt = 0; qt < 2; ++qt)
                cacc[db][qt] = __builtin_amdgcn_mfma_f32_16x16x32_bf16(
                    va[db], pa[qt], cacc[db][qt], 0, 0, 0);
    }

    // L: reduce across quads (lanes sharing l16), then across waves via LDS
#pragma unroll
    for (int qt = 0; qt < 2; ++qt) {
        lsum[qt] += __shfl_xor(lsum[qt], 16);
        lsum[qt] += __shfl_xor(lsum[qt], 32);
    }
    if (lane < 16) {
#pragma unroll
        for (int qt = 0; qt < 2; ++qt) wp[wv][qt][lane] = lsum[qt];
    }
    __syncthreads();
    if (tid < 32) {
        int qt = tid >> 4, row = tid & 15;
        float L = wp[0][qt][row] + wp[1][qt][row] + wp[2][qt][row] + wp[3][qt][row];
        Li[hb + q0 + qt*16 + row] = L;
        linvs[qt][row] = 1.0f / fmaxf(L, 1e-30f);
    }

    // cross-wave ctx reduce + normalize + write, one q-tile at a time
#pragma unroll
    for (int qt = 0; qt < 2; ++qt) {
        __syncthreads();   // also orders linvs writes before first combine
#pragma unroll
        for (int db = 0; db < 4; ++db)
#pragma unroll
            for (int r = 0; r < 4; ++r)
                ctxp[wv][(db*16 + quad*4 + r) * 17 + l16] = cacc[db][qt][r];
        __syncthreads();
        {
            const int q  = tid >> 4;          // 0..15
            const int d0 = (tid & 15) * 4;    // 0,4,..,60
            const float lv = linvs[qt][q];
            bf16x4 pk;
#pragma unroll
            for (int i = 0; i < 4; ++i) {
                const int e = (d0 + i) * 17 + q;
                pk[i] = (bf16)((ctxp[0][e] + ctxp[1][e] + ctxp[2][e] + ctxp[3][e]) * lv);
            }
            *(bf16x4*)(ctxOut + (hb + q0 + qt*16 + q) * DK_ + d0) = pk;
        }
    }
}

// ---------------------------------------------------------------------------
// Head-mean attention weights. 32-q-row blocks (1024 total), XCD-swizzled so
// each XCD owns one j-chunk (K rows for all heads L2-resident); Q streams.
// Small state (asum 32 + qf 16) under __launch_bounds__(256,4).
// Swapped QK^T: lane holds 4 CONSECUTIVE j for its q -> f32x4 stores; linv
// hoisted per (h,q) with 1/H folded in; bare exp2 (scale folded into Q).
// ---------------------------------------------------------------------------
__global__ __launch_bounds__(256, 4)
void attn_weights(const bf16* __restrict__ Q, const bf16* __restrict__ K,
                  const float* __restrict__ Li, float* __restrict__ attnOut)
{
    // 1024 blocks: l = q-tile32 (64) x b (2) x j-chunk256 (8); each XCD gets
    // 128 consecutive l = one j-chunk, all q, both b. Bijective.
    const int bid = blockIdx.x;
    const int l   = (bid & 7) * 128 + (bid >> 3);
    const int q0  = (l & 63) * 32;
    const int b   = (l >> 6) & 1;
    const int j0  = (l >> 7) * 256;

    const int tid = threadIdx.x;
    const int wv = tid >> 6, lane = tid & 63, quad = lane >> 4, l16 = lane & 15;

    __shared__ float linv[H_][32];
#pragma unroll
    for (int i = 0; i < 2; ++i) {
        int idx = tid * 2 + i;
        int hh = idx >> 5, row = idx & 31;
        linv[hh][row] = (1.0f / H_) /
            fmaxf(Li[(size_t)(b * H_ + hh) * S_ + q0 + row], 1e-30f);
    }
    __syncthreads();

    f32x4 asum[2][4];
#pragma unroll
    for (int qt = 0; qt < 2; ++qt)
#pragma unroll
        for (int t = 0; t < 4; ++t) asum[qt][t] = f32x4{0.f,0.f,0.f,0.f};

    for (int h = 0; h < H_; ++h) {
        const size_t hb = (size_t)(b * H_ + h) * S_;
        bf16x8 qf[2][2];
        float lv[2];
#pragma unroll
        for (int qt = 0; qt < 2; ++qt) {
            const bf16* qrow = Q + (hb + q0 + qt*16 + l16) * DK_;
            qf[qt][0] = ld8(qrow + quad*8);
            qf[qt][1] = ld8(qrow + 32 + quad*8);
            lv[qt] = linv[h][qt*16 + l16];
        }
        const bf16* Kb = K + hb * DK_;
#pragma unroll
        for (int t = 0; t < 4; ++t) {
            const int jl = j0 + wv*64 + t*16;
            const bf16* krow = Kb + (size_t)(jl + l16) * DK_;
            bf16x8 kfa = ld8(krow + quad*8), kfb = ld8(krow + 32 + quad*8);
#pragma unroll
            for (int qt = 0; qt < 2; ++qt) {
                f32x4 z = {0.f,0.f,0.f,0.f};
                z = __builtin_amdgcn_mfma_f32_16x16x32_bf16(kfa, qf[qt][0], z, 0, 0, 0);
                f32x4 s = __builtin_amdgcn_mfma_f32_16x16x32_bf16(kfb, qf[qt][1], z, 0, 0, 0);
#pragma unroll
                for (int r = 0; r < 4; ++r)
                    asum[qt][t][r] += __builtin_amdgcn_exp2f(fminf(s[r], 86.f)) * lv[qt];
            }
        }
    }
#pragma unroll
    for (int qt = 0; qt < 2; ++qt)
#pragma unroll
        for (int t = 0; t < 4; ++t)
            *(f32x4*)(attnOut + ((size_t)b * S_ + q0 + qt*16 + l16) * S_
                      + j0 + wv*64 + t*16 + quad*4) = asum[qt][t];
}

// ---------------------------------------------------------------------------
extern "C" void kernel_launch(void* const* d_in, const int* in_sizes, int n_in,
                              void* d_out, int out_size, void* d_ws, size_t ws_size,
                              hipStream_t stream)
{
    (void)in_sizes; (void)n_in; (void)out_size; (void)ws_size;

    const float* query = (const float*)d_in[0];
    const float* key_t = (const float*)d_in[1];
    const float* value = (const float*)d_in[2];
    const float* Wq = (const float*)d_in[3];
    const float* bq = (const float*)d_in[4];
    const float* Wk = (const float*)d_in[5];
    const float* bk = (const float*)d_in[6];
    const float* Wv = (const float*)d_in[7];
    const float* bv = (const float*)d_in[8];
    const float* Wo = (const float*)d_in[9];
    const float* bo = (const float*)d_in[10];

    float* out     = (float*)d_out;                  // (B,S,D) fp32
    float* attnOut = out + (size_t)B_ * S_ * D_;     // (B,S,S) fp32

    const size_t nX = (size_t)B_ * S_ * D_;
    const size_t nW = (size_t)D_ * D_;

    // d_out doubles as scratch for bf16 X-converts (dead before overwrites)
    bf16* Xqb = (bf16*)d_out;
    bf16* Xkb = Xqb + nX;
    bf16* Xvb = Xkb + nX;

    // ws: Qh,Kh,VtH (25.2MB) + Wob (2.1MB) + Li (0.26MB) + [Wqb/Wkb/Wvb
    // overlaid by CtxH (8.4MB) -- W converts are dead before attn_ctx runs].
    bf16* Qh  = (bf16*)d_ws;
    bf16* Kh  = Qh + nX;
    bf16* VtH = Kh + nX;                             // V^T (B,H,DK,S)
    bf16* Wob = VtH + nX;
    float* Li = (float*)(Wob + nW);
    bf16* Wqb = (bf16*)(Li + (size_t)B_ * H_ * S_);
    bf16* Wkb = Wqb + nW;
    bf16* Wvb = Wkb + nW;
    bf16* CtxH = Wqb;                                // overlays dead W converts

    cvt_all<<<8192, 256, 0, stream>>>(query, key_t, value, Wq, Wk, Wv, Wo,
                                      Xqb, Xkb, Xvb, Wqb, Wkb, Wvb, Wob);
    dim3 gg(M_/128, D_/128);
    // Q pre-scaled by 1/sqrt(DK) * log2(e): softmax scale + exp->exp2 fold
    gemm128<<<gg, 256, 0, stream>>>(Xqb, Wqb, bq, Qh, 0, 0, 0.18033688011112042f);
    gemm128<<<gg, 256, 0, stream>>>(Xkb, Wkb, bk, Kh, 0, 0, 1.0f);
    gemm128<<<gg, 256, 0, stream>>>(Xvb, Wvb, bv, VtH, 0, 2, 1.0f);   // V^T
    attn_ctx    <<<2048, 256, 0, stream>>>(Qh, Kh, VtH, Li, CtxH);
    attn_weights<<<1024, 256, 0, stream>>>(Qh, Kh, Li, attnOut);
    gemm128<<<gg, 256, 0, stream>>>(CtxH, Wob, bo, out, 1, 1, 1.0f);
}

// Round 6
// 377.117 us; speedup vs baseline: 1.3096x; 1.3096x over previous
//
#include <hip/hip_runtime.h>

// Problem constants (B,S,D,H from reference)
#define B_ 2
#define S_ 2048
#define D_ 1024
#define H_ 16
#define DK_ 64
#define M_ (B_ * S_)      // 4096 rows in the projection GEMMs

typedef __bf16 bf16;
typedef __attribute__((ext_vector_type(8))) __bf16 bf16x8;
typedef __attribute__((ext_vector_type(4))) __bf16 bf16x4;
typedef __attribute__((ext_vector_type(4))) float f32x4;

static __device__ __forceinline__ bf16x8 ld8(const bf16* p) {
    return *(const bf16x8*)p;   // 16B aligned by construction
}

// Async global->LDS, 16B per lane. LDS dest = wave-uniform base + lane*16
// (linear); global src is per-lane (carries the swizzle).
static __device__ __forceinline__ void g2l16(const void* g, void* l) {
    __builtin_amdgcn_global_load_lds(
        (const __attribute__((address_space(1))) unsigned int*)g,
        (__attribute__((address_space(3))) unsigned int*)l, 16, 0, 0);
}

// ---------------------------------------------------------------------------
// Elementwise fp32 -> bf16 for the 3 X inputs (into d_out scratch) and the
// 4 weight matrices (into ws). Block mapping: 3*2048 X-blocks + 4*512 W-blocks.
// ---------------------------------------------------------------------------
__global__ __launch_bounds__(256)
void cvt_all(const float* __restrict__ xq, const float* __restrict__ xk,
             const float* __restrict__ xv, const float* __restrict__ wq,
             const float* __restrict__ wk, const float* __restrict__ wv,
             const float* __restrict__ wo, bf16* __restrict__ xqo,
             bf16* __restrict__ xko, bf16* __restrict__ xvo,
             bf16* __restrict__ wqo, bf16* __restrict__ wko,
             bf16* __restrict__ wvo, bf16* __restrict__ woo)
{
    const int bx = blockIdx.x;
    const float* s; bf16* d; size_t base;
    if (bx < 6144) {
        int a = bx >> 11;
        s = (a == 0) ? xq : (a == 1) ? xk : xv;
        d = (a == 0) ? xqo : (a == 1) ? xko : xvo;
        base = (size_t)(bx & 2047) * 2048;
    } else {
        int a = (bx - 6144) >> 9;
        s = (a == 0) ? wq : (a == 1) ? wk : (a == 2) ? wv : wo;
        d = (a == 0) ? wqo : (a == 1) ? wko : (a == 2) ? wvo : woo;
        base = (size_t)((bx - 6144) & 511) * 2048;
    }
    size_t i = base + (size_t)threadIdx.x * 8;
    f32x4 a4 = *(const f32x4*)(s + i);
    f32x4 b4 = *(const f32x4*)(s + i + 4);
    bf16x8 r;
    r[0]=(bf16)a4[0]; r[1]=(bf16)a4[1]; r[2]=(bf16)a4[2]; r[3]=(bf16)a4[3];
    r[4]=(bf16)b4[0]; r[5]=(bf16)b4[1]; r[6]=(bf16)b4[2]; r[7]=(bf16)b4[3];
    *(bf16x8*)(d + i) = r;
}

// ---------------------------------------------------------------------------
// 128x128-tile bf16 GEMM, LDS-staged, 2-barrier K-loop.
// out_mode: 0 = bf16 head-split (B,H,S,DK);  1 = fp32 flat (M,N);
//           2 = bf16 TRANSPOSED head-split (B,H,DK,S)  [for V^T]
// a_headsplit: A element (m,k) at ((b*H+h)*S+s)*DK+dk (ctx layout).
// scale: applied after bias. Q gemm folds 0.125*log2(e) (softmax 1/sqrt(DK)
//        plus the exp->exp2 conversion factor).
// ---------------------------------------------------------------------------
__global__ __launch_bounds__(256)
void gemm128(const bf16* __restrict__ A, const bf16* __restrict__ W,
             const float* __restrict__ bias, void* __restrict__ out,
             int a_headsplit, int out_mode, float scale)
{
    const int m0 = blockIdx.x * 128, n0 = blockIdx.y * 128;
    const int tid = threadIdx.x;
    const int wv = tid >> 6, lane = tid & 63, quad = lane >> 4, l16 = lane & 15;
    const int wr = (wv >> 1) * 64, wc = (wv & 1) * 64;

    __shared__ bf16 As[128 * 32];
    __shared__ bf16 Bs[128 * 32];

    f32x4 acc[4][4];
#pragma unroll
    for (int i = 0; i < 4; ++i)
#pragma unroll
        for (int j = 0; j < 4; ++j) acc[i][j] = f32x4{0.f, 0.f, 0.f, 0.f};

    const int srow = tid >> 2;
    const int scol = (tid & 3) * 8;

    for (int k0 = 0; k0 < D_; k0 += 32) {
        bf16x8 av[2], bw[2];
#pragma unroll
        for (int c = 0; c < 2; ++c) {
            const int row = c * 64 + srow;
            const int k   = k0 + scol;
            const bf16* ap;
            if (a_headsplit) {
                int m = m0 + row, bb = m >> 11, ss = m & (S_ - 1);
                int hh = k >> 6, dd = k & (DK_ - 1);
                ap = A + (((size_t)(bb * H_ + hh) * S_ + ss) * DK_ + dd);
            } else {
                ap = A + (size_t)(m0 + row) * D_ + k;
            }
            av[c] = ld8(ap);
            bw[c] = ld8(W + (size_t)(n0 + row) * D_ + k);
        }
        __syncthreads();
#pragma unroll
        for (int c = 0; c < 2; ++c) {
            const int e = c * 2048 + tid * 8;
            *(bf16x8*)(As + e) = av[c];
            *(bf16x8*)(Bs + e) = bw[c];
        }
        __syncthreads();

        bf16x8 af[4], bfr[4];
#pragma unroll
        for (int i = 0; i < 4; ++i)
            af[i] = *(const bf16x8*)(As + (wr + i*16 + l16) * 32 + quad * 8);
#pragma unroll
        for (int j = 0; j < 4; ++j)
            bfr[j] = *(const bf16x8*)(Bs + (wc + j*16 + l16) * 32 + quad * 8);
#pragma unroll
        for (int i = 0; i < 4; ++i)
#pragma unroll
            for (int j = 0; j < 4; ++j)
                acc[i][j] = __builtin_amdgcn_mfma_f32_16x16x32_bf16(
                    af[i], bfr[j], acc[i][j], 0, 0, 0);
    }

#pragma unroll
    for (int i = 0; i < 4; ++i)
#pragma unroll
        for (int j = 0; j < 4; ++j) {
            const int nn = n0 + wc + j*16 + l16;
            const float bvv = bias[nn];
            const int mm0 = m0 + wr + i*16 + quad*4;   // 4-aligned, same b
            if (out_mode == 2) {
                // V^T: (B,H,DK,S); 4 consecutive tokens -> one 8B store
                bf16x4 pk;
#pragma unroll
                for (int r = 0; r < 4; ++r)
                    pk[r] = (bf16)((acc[i][j][r] + bvv) * scale);
                int bb = mm0 >> 11, ss = mm0 & (S_ - 1);
                int hh = nn >> 6,  dd = nn & (DK_ - 1);
                *(bf16x4*)((bf16*)out +
                    ((size_t)(bb * H_ + hh) * DK_ + dd) * S_ + ss) = pk;
            } else {
#pragma unroll
                for (int r = 0; r < 4; ++r) {
                    const int mm = mm0 + r;
                    float v = (acc[i][j][r] + bvv) * scale;
                    if (out_mode == 1) {
                        ((float*)out)[(size_t)mm * D_ + nn] = v;
                    } else {
                        int bb = mm >> 11, ss = mm & (S_ - 1);
                        int hh = nn >> 6, dd = nn & (DK_ - 1);
                        ((bf16*)out)[((size_t)(bb * H_ + hh) * S_ + ss) * DK_ + dd] = (bf16)v;
                    }
                }
            }
        }
}

// ---------------------------------------------------------------------------
// Context + softmax denominators, fused.
// Block = 64 q-rows, one (h,b); 4 waves; EACH WAVE OWNS 16 q-ROWS over the
// FULL j-range (no cross-wave reduce, no epilogue LDS at all). K and V^T
// chunks (32 j) are shared by all 4 waves: staged via async global_load_lds
// into double-buffered LDS (m97 2-phase: stage next -> compute cur ->
// barrier). LDS layouts XOR-swizzled at 16B granularity; the swizzle is
// applied to the per-lane GLOBAL source address (linear LDS dest, rule #21)
// and re-applied on the ds_read side. K reads: 2-way (free); V reads: 4-way.
// Swapped QK^T: s = mfma(K,Q) puts P[j=quad*4+r][q=l16] in registers. PV
// uses the custom k->j bijection (k=quad*8+t*4+r <-> j=t*16+quad*4+r), so P
// feeds PV straight from registers. Scores pre-scaled by 0.125*log2e in the
// Q projection -> bare v_exp2. P~ UNNORMALIZED; per-lane row-sum L reduced
// with 2 shuffles in the epilogue; ctx normalized + written from registers.
// Round-4 lesson: no launch_bounds min-waves (register cap serialized it);
// small natural state (~110 regs: qf 16 + cacc 16 + transients) instead.
// ---------------------------------------------------------------------------
__global__ __launch_bounds__(256)
void attn_ctx(const bf16* __restrict__ Q, const bf16* __restrict__ K,
              const bf16* __restrict__ Vt, float* __restrict__ Li,
              bf16* __restrict__ ctxOut)
{
    // 1024 blocks; bid%8 = XCD; each XCD gets 128 consecutive semantic idx
    // = 4 full (h,b) groups -> K/V (512KB each) L2-resident per XCD.
    const int bid = blockIdx.x;
    const int l   = (bid & 7) * 128 + (bid >> 3);
    const int q0  = (l & 31) * 64;
    const int h   = (l >> 5) & 15;
    const int b   = l >> 9;

    const int tid = threadIdx.x;
    const int wv = tid >> 6, lane = tid & 63, quad = lane >> 4, l16 = lane & 15;

    __shared__ bf16 Kl[2][2048];   // [buf][32 j][64 dk], 16B-swizzled rows
    __shared__ bf16 Vl[2][2048];   // [buf][64 d][32 j],  16B-swizzled rows

    const size_t hb = (size_t)(b * H_ + h) * S_;
    const int qw = q0 + wv * 16;   // this wave's 16 q-rows

    bf16x8 qf0, qf1;
    {
        const bf16* qrow = Q + (hb + qw + l16) * DK_;
        qf0 = ld8(qrow + quad*8);
        qf1 = ld8(qrow + 32 + quad*8);
    }
    const bf16* Kb  = K  + hb * DK_;
    const bf16* Vtb = Vt + hb * DK_;   // (B,H,DK,S): row d at Vtb + d*S

    f32x4 cacc[4];      // [db]  C[dk = db*16+quad*4+r][q = l16]
#pragma unroll
    for (int db = 0; db < 4; ++db) cacc[db] = f32x4{0.f,0.f,0.f,0.f};
    float lsum = 0.f;

    // --- staging lane constants (LDS linear slot o = wv*1024 + lane*16) ---
    // K: j = o>>7 = wv*8 + (lane>>3); in-row byte = (lane&7)*16,
    //    source swizzled by ^((j&7)<<4)
    const int kj = wv*8 + (lane >> 3);
    const int koff = (((lane & 7) ^ (lane >> 3)) << 4);
    // V: d = o>>6 = wv*16 + (lane>>2); in-row byte = (lane&3)*16,
    //    source swizzled by ^((d&3)<<4)
    const int vd = wv*16 + (lane >> 2);
    const int voff = (((lane & 3) ^ ((lane >> 2) & 3)) << 4);

    const char* Kbc = (const char*)Kb;
    const char* Vbc = (const char*)Vtb;

#define STAGE(jc, buf)                                                       \
    do {                                                                     \
        g2l16(Kbc + ((size_t)(jc) * 32 + kj) * 128 + koff,                   \
              &Kl[buf][wv * 512]);                                           \
        g2l16(Vbc + (size_t)vd * (S_ * 2) + (size_t)(jc) * 64 + voff,        \
              &Vl[buf][wv * 512]);                                           \
    } while (0)

    STAGE(0, 0);
    __syncthreads();   // drains vmcnt(0): buf0 ready

    int cur = 0;
    const int swk = (l16 & 7) << 4;
    const int swv = (l16 & 3) << 4;
    for (int jc = 0; jc < 64; ++jc) {
        STAGE((jc + 1) & 63, cur ^ 1);   // async; drained at the barrier

        const char* kb = (const char*)&Kl[cur][0];
        const char* vb = (const char*)&Vl[cur][0];
        bf16x8 kf0a = *(const bf16x8*)(kb + l16*128 + ((quad*16) ^ swk));
        bf16x8 kf0b = *(const bf16x8*)(kb + l16*128 + ((64 + quad*16) ^ swk));
        bf16x8 kf1a = *(const bf16x8*)(kb + (16+l16)*128 + ((quad*16) ^ swk));
        bf16x8 kf1b = *(const bf16x8*)(kb + (16+l16)*128 + ((64 + quad*16) ^ swk));

        f32x4 z0 = {0.f,0.f,0.f,0.f}, z1 = {0.f,0.f,0.f,0.f};
        z0 = __builtin_amdgcn_mfma_f32_16x16x32_bf16(kf0a, qf0, z0, 0, 0, 0);
        f32x4 s0 = __builtin_amdgcn_mfma_f32_16x16x32_bf16(kf0b, qf1, z0, 0, 0, 0);
        z1 = __builtin_amdgcn_mfma_f32_16x16x32_bf16(kf1a, qf0, z1, 0, 0, 0);
        f32x4 s1 = __builtin_amdgcn_mfma_f32_16x16x32_bf16(kf1b, qf1, z1, 0, 0, 0);

        float e0 = __builtin_amdgcn_exp2f(fminf(s0[0], 86.f));
        float e1 = __builtin_amdgcn_exp2f(fminf(s0[1], 86.f));
        float e2 = __builtin_amdgcn_exp2f(fminf(s0[2], 86.f));
        float e3 = __builtin_amdgcn_exp2f(fminf(s0[3], 86.f));
        float e4 = __builtin_amdgcn_exp2f(fminf(s1[0], 86.f));
        float e5 = __builtin_amdgcn_exp2f(fminf(s1[1], 86.f));
        float e6 = __builtin_amdgcn_exp2f(fminf(s1[2], 86.f));
        float e7 = __builtin_amdgcn_exp2f(fminf(s1[3], 86.f));
        lsum += ((e0 + e1) + (e2 + e3)) + ((e4 + e5) + (e6 + e7));
        bf16x8 pa;
        pa[0]=(bf16)e0; pa[1]=(bf16)e1; pa[2]=(bf16)e2; pa[3]=(bf16)e3;
        pa[4]=(bf16)e4; pa[5]=(bf16)e5; pa[6]=(bf16)e6; pa[7]=(bf16)e7;

#pragma unroll
        for (int db = 0; db < 4; ++db) {
            const int d = db*16 + l16;
            bf16x4 vlo = *(const bf16x4*)(vb + d*64 + ((quad*8) ^ swv));
            bf16x4 vhi = *(const bf16x4*)(vb + d*64 + (((32 + quad*8)) ^ swv));
            bf16x8 va = __builtin_shufflevector(vlo, vhi, 0,1,2,3,4,5,6,7);
            cacc[db] = __builtin_amdgcn_mfma_f32_16x16x32_bf16(
                va, pa, cacc[db], 0, 0, 0);
        }

        __syncthreads();   // drains stage vmcnt + all waves done with cur
        cur ^= 1;
    }
#undef STAGE

    // L reduce across quads (lanes sharing l16): all lanes end with their row
    lsum += __shfl_xor(lsum, 16);
    lsum += __shfl_xor(lsum, 32);
    const float linv = 1.0f / fmaxf(lsum, 1e-30f);
    if (lane < 16) Li[hb + qw + lane] = lsum;

    // normalize + write straight from registers (8B stores, dk contiguous)
#pragma unroll
    for (int db = 0; db < 4; ++db) {
        bf16x4 pk;
#pragma unroll
        for (int r = 0; r < 4; ++r) pk[r] = (bf16)(cacc[db][r] * linv);
        *(bf16x4*)(ctxOut + (hb + qw + l16) * DK_ + db*16 + quad*4) = pk;
    }
}

// ---------------------------------------------------------------------------
// Head-mean attention weights (round-3 shape). 1D grid, XCD-swizzled so each
// XCD owns one j-chunk (K rows for all heads L2-resident); Q streams.
// Swapped QK^T: lane holds 4 CONSECUTIVE j for its q -> f32x4 stores; linv
// hoisted per (h,q) with 1/H folded in; bare exp2 (scale folded into Q).
// ---------------------------------------------------------------------------
__global__ __launch_bounds__(256)
void attn_weights(const bf16* __restrict__ Q, const bf16* __restrict__ K,
                  const float* __restrict__ Li, float* __restrict__ attnOut)
{
    // 512 blocks: l = q-tile (32) x b (2) x j-chunk (8); each XCD gets 64
    // consecutive l = one j-chunk, both b. Bijective.
    const int bid = blockIdx.x;
    const int l   = (bid & 7) * 64 + (bid >> 3);
    const int q0  = (l & 31) * 64;
    const int b   = (l >> 5) & 1;
    const int j0  = (l >> 6) * 256;

    const int tid = threadIdx.x;
    const int wv = tid >> 6, lane = tid & 63, quad = lane >> 4, l16 = lane & 15;

    __shared__ float linv[H_][64];
#pragma unroll
    for (int i = 0; i < 4; ++i) {
        int idx = tid * 4 + i;
        int hh = idx >> 6, row = idx & 63;
        linv[hh][row] = (1.0f / H_) /
            fmaxf(Li[(size_t)(b * H_ + hh) * S_ + q0 + row], 1e-30f);
    }
    __syncthreads();

    f32x4 asum[4][4];
#pragma unroll
    for (int qt = 0; qt < 4; ++qt)
#pragma unroll
        for (int t = 0; t < 4; ++t) asum[qt][t] = f32x4{0.f,0.f,0.f,0.f};

    for (int h = 0; h < H_; ++h) {
        const size_t hb = (size_t)(b * H_ + h) * S_;
        bf16x8 qf[4][2];
        float lv[4];
#pragma unroll
        for (int qt = 0; qt < 4; ++qt) {
            const bf16* qrow = Q + (hb + q0 + qt*16 + l16) * DK_;
            qf[qt][0] = ld8(qrow + quad*8);
            qf[qt][1] = ld8(qrow + 32 + quad*8);
            lv[qt] = linv[h][qt*16 + l16];
        }
        const bf16* Kb = K + hb * DK_;
#pragma unroll
        for (int t = 0; t < 4; ++t) {
            const int jl = j0 + wv*64 + t*16;
            const bf16* krow = Kb + (size_t)(jl + l16) * DK_;
            bf16x8 kfa = ld8(krow + quad*8), kfb = ld8(krow + 32 + quad*8);
#pragma unroll
            for (int qt = 0; qt < 4; ++qt) {
                f32x4 z = {0.f,0.f,0.f,0.f};
                z = __builtin_amdgcn_mfma_f32_16x16x32_bf16(kfa, qf[qt][0], z, 0, 0, 0);
                f32x4 s = __builtin_amdgcn_mfma_f32_16x16x32_bf16(kfb, qf[qt][1], z, 0, 0, 0);
#pragma unroll
                for (int r = 0; r < 4; ++r)
                    asum[qt][t][r] += __builtin_amdgcn_exp2f(fminf(s[r], 86.f)) * lv[qt];
            }
        }
    }
#pragma unroll
    for (int qt = 0; qt < 4; ++qt)
#pragma unroll
        for (int t = 0; t < 4; ++t)
            *(f32x4*)(attnOut + ((size_t)b * S_ + q0 + qt*16 + l16) * S_
                      + j0 + wv*64 + t*16 + quad*4) = asum[qt][t];
}

// ---------------------------------------------------------------------------
extern "C" void kernel_launch(void* const* d_in, const int* in_sizes, int n_in,
                              void* d_out, int out_size, void* d_ws, size_t ws_size,
                              hipStream_t stream)
{
    (void)in_sizes; (void)n_in; (void)out_size; (void)ws_size;

    const float* query = (const float*)d_in[0];
    const float* key_t = (const float*)d_in[1];
    const float* value = (const float*)d_in[2];
    const float* Wq = (const float*)d_in[3];
    const float* bq = (const float*)d_in[4];
    const float* Wk = (const float*)d_in[5];
    const float* bk = (const float*)d_in[6];
    const float* Wv = (const float*)d_in[7];
    const float* bv = (const float*)d_in[8];
    const float* Wo = (const float*)d_in[9];
    const float* bo = (const float*)d_in[10];

    float* out     = (float*)d_out;                  // (B,S,D) fp32
    float* attnOut = out + (size_t)B_ * S_ * D_;     // (B,S,S) fp32

    const size_t nX = (size_t)B_ * S_ * D_;
    const size_t nW = (size_t)D_ * D_;

    // d_out doubles as scratch for bf16 X-converts (dead before overwrites)
    bf16* Xqb = (bf16*)d_out;
    bf16* Xkb = Xqb + nX;
    bf16* Xvb = Xkb + nX;

    // ws: Qh,Kh,VtH (25.2MB) + Wob (2.1MB) + Li (0.26MB) + [Wqb/Wkb/Wvb
    // overlaid by CtxH (8.4MB) -- W converts are dead before attn_ctx runs].
    bf16* Qh  = (bf16*)d_ws;
    bf16* Kh  = Qh + nX;
    bf16* VtH = Kh + nX;                             // V^T (B,H,DK,S)
    bf16* Wob = VtH + nX;
    float* Li = (float*)(Wob + nW);
    bf16* Wqb = (bf16*)(Li + (size_t)B_ * H_ * S_);
    bf16* Wkb = Wqb + nW;
    bf16* Wvb = Wkb + nW;
    bf16* CtxH = Wqb;                                // overlays dead W converts

    cvt_all<<<8192, 256, 0, stream>>>(query, key_t, value, Wq, Wk, Wv, Wo,
                                      Xqb, Xkb, Xvb, Wqb, Wkb, Wvb, Wob);
    dim3 gg(M_/128, D_/128);
    // Q pre-scaled by 1/sqrt(DK) * log2(e): softmax scale + exp->exp2 fold
    gemm128<<<gg, 256, 0, stream>>>(Xqb, Wqb, bq, Qh, 0, 0, 0.18033688011112042f);
    gemm128<<<gg, 256, 0, stream>>>(Xkb, Wkb, bk, Kh, 0, 0, 1.0f);
    gemm128<<<gg, 256, 0, stream>>>(Xvb, Wvb, bv, VtH, 0, 2, 1.0f);   // V^T
    attn_ctx    <<<1024, 256, 0, stream>>>(Qh, Kh, VtH, Li, CtxH);
    attn_weights<<<512, 256, 0, stream>>>(Qh, Kh, Li, attnOut);
    gemm128<<<gg, 256, 0, stream>>>(CtxH, Wob, bo, out, 1, 1, 1.0f);
}

// Round 7
// 342.672 us; speedup vs baseline: 1.4413x; 1.1005x over previous
//
#include <hip/hip_runtime.h>

// Problem constants (B,S,D,H from reference)
#define B_ 2
#define S_ 2048
#define D_ 1024
#define H_ 16
#define DK_ 64
#define M_ (B_ * S_)      // 4096 rows in the projection GEMMs

typedef __bf16 bf16;
typedef __attribute__((ext_vector_type(8))) __bf16 bf16x8;
typedef __attribute__((ext_vector_type(4))) __bf16 bf16x4;
typedef __attribute__((ext_vector_type(4))) float f32x4;

static __device__ __forceinline__ bf16x8 ld8(const bf16* p) {
    return *(const bf16x8*)p;   // 16B aligned by construction
}

// Async global->LDS, 16B per lane. LDS dest = wave-uniform base + lane*16
// (linear); global src is per-lane (carries the swizzle).
static __device__ __forceinline__ void g2l16(const void* g, void* l) {
    __builtin_amdgcn_global_load_lds(
        (const __attribute__((address_space(1))) unsigned int*)g,
        (__attribute__((address_space(3))) unsigned int*)l, 16, 0, 0);
}

// ---------------------------------------------------------------------------
// Elementwise fp32 -> bf16 for the 3 X inputs (into d_out scratch) and the
// 4 weight matrices (into ws). Block mapping: 3*2048 X-blocks + 4*512 W-blocks.
// ---------------------------------------------------------------------------
__global__ __launch_bounds__(256)
void cvt_all(const float* __restrict__ xq, const float* __restrict__ xk,
             const float* __restrict__ xv, const float* __restrict__ wq,
             const float* __restrict__ wk, const float* __restrict__ wv,
             const float* __restrict__ wo, bf16* __restrict__ xqo,
             bf16* __restrict__ xko, bf16* __restrict__ xvo,
             bf16* __restrict__ wqo, bf16* __restrict__ wko,
             bf16* __restrict__ wvo, bf16* __restrict__ woo)
{
    const int bx = blockIdx.x;
    const float* s; bf16* d; size_t base;
    if (bx < 6144) {
        int a = bx >> 11;
        s = (a == 0) ? xq : (a == 1) ? xk : xv;
        d = (a == 0) ? xqo : (a == 1) ? xko : xvo;
        base = (size_t)(bx & 2047) * 2048;
    } else {
        int a = (bx - 6144) >> 9;
        s = (a == 0) ? wq : (a == 1) ? wk : (a == 2) ? wv : wo;
        d = (a == 0) ? wqo : (a == 1) ? wko : (a == 2) ? wvo : woo;
        base = (size_t)((bx - 6144) & 511) * 2048;
    }
    size_t i = base + (size_t)threadIdx.x * 8;
    f32x4 a4 = *(const f32x4*)(s + i);
    f32x4 b4 = *(const f32x4*)(s + i + 4);
    bf16x8 r;
    r[0]=(bf16)a4[0]; r[1]=(bf16)a4[1]; r[2]=(bf16)a4[2]; r[3]=(bf16)a4[3];
    r[4]=(bf16)b4[0]; r[5]=(bf16)b4[1]; r[6]=(bf16)b4[2]; r[7]=(bf16)b4[3];
    *(bf16x8*)(d + i) = r;
}

// ---------------------------------------------------------------------------
// 128x128-tile bf16 GEMM, LDS-staged, 2-barrier K-loop.
// out_mode: 0 = bf16 head-split (B,H,S,DK);  1 = fp32 flat (M,N);
//           2 = bf16 V^T head-split (B,H,DK,S) with PAIR-INTERLEAVED tokens:
//               within each 32-token block, element order is
//               (j0,j0+16,j0+1,j0+17,...,j0+15,j0+31)  [pos=2*(j&15)+(j>>4)].
//               This makes attn_ctx's PV fragment one contiguous 16B read.
// a_headsplit: A element (m,k) at ((b*H+h)*S+s)*DK+dk (ctx layout).
// scale: applied after bias. Q gemm folds 0.125*log2(e) (softmax 1/sqrt(DK)
//        plus the exp->exp2 conversion factor).
// ---------------------------------------------------------------------------
__global__ __launch_bounds__(256)
void gemm128(const bf16* __restrict__ A, const bf16* __restrict__ W,
             const float* __restrict__ bias, void* __restrict__ out,
             int a_headsplit, int out_mode, float scale)
{
    const int m0 = blockIdx.x * 128, n0 = blockIdx.y * 128;
    const int tid = threadIdx.x;
    const int wv = tid >> 6, lane = tid & 63, quad = lane >> 4, l16 = lane & 15;
    const int wr = (wv >> 1) * 64, wc = (wv & 1) * 64;

    __shared__ bf16 As[128 * 32];
    __shared__ bf16 Bs[128 * 32];

    f32x4 acc[4][4];
#pragma unroll
    for (int i = 0; i < 4; ++i)
#pragma unroll
        for (int j = 0; j < 4; ++j) acc[i][j] = f32x4{0.f, 0.f, 0.f, 0.f};

    const int srow = tid >> 2;
    const int scol = (tid & 3) * 8;

    for (int k0 = 0; k0 < D_; k0 += 32) {
        bf16x8 av[2], bw[2];
#pragma unroll
        for (int c = 0; c < 2; ++c) {
            const int row = c * 64 + srow;
            const int k   = k0 + scol;
            const bf16* ap;
            if (a_headsplit) {
                int m = m0 + row, bb = m >> 11, ss = m & (S_ - 1);
                int hh = k >> 6, dd = k & (DK_ - 1);
                ap = A + (((size_t)(bb * H_ + hh) * S_ + ss) * DK_ + dd);
            } else {
                ap = A + (size_t)(m0 + row) * D_ + k;
            }
            av[c] = ld8(ap);
            bw[c] = ld8(W + (size_t)(n0 + row) * D_ + k);
        }
        __syncthreads();
#pragma unroll
        for (int c = 0; c < 2; ++c) {
            const int e = c * 2048 + tid * 8;
            *(bf16x8*)(As + e) = av[c];
            *(bf16x8*)(Bs + e) = bw[c];
        }
        __syncthreads();

        bf16x8 af[4], bfr[4];
#pragma unroll
        for (int i = 0; i < 4; ++i)
            af[i] = *(const bf16x8*)(As + (wr + i*16 + l16) * 32 + quad * 8);
#pragma unroll
        for (int j = 0; j < 4; ++j)
            bfr[j] = *(const bf16x8*)(Bs + (wc + j*16 + l16) * 32 + quad * 8);
#pragma unroll
        for (int i = 0; i < 4; ++i)
#pragma unroll
            for (int j = 0; j < 4; ++j)
                acc[i][j] = __builtin_amdgcn_mfma_f32_16x16x32_bf16(
                    af[i], bfr[j], acc[i][j], 0, 0, 0);
    }

    if (out_mode == 2) {
        // V^T pair-interleaved: i-tiles 2ip (tokens s..s+15 region) and 2ip+1
        // (s+16..s+31) share a 32-token block; interleaving their r-elements
        // gives one contiguous 16B store at pos-base 2*(s&15).
#pragma unroll
        for (int j = 0; j < 4; ++j) {
            const int nn = n0 + wc + j*16 + l16;      // d index
            const float bvv = bias[nn];
            int hh = nn >> 6, dd = nn & (DK_ - 1);
#pragma unroll
            for (int ip = 0; ip < 2; ++ip) {
                const int mlo = m0 + wr + 32*ip + quad*4;   // token of (2ip, r=0)
                int bb = mlo >> 11, sl = mlo & (S_ - 1);
                int g0 = (sl & ~31) + ((sl & 15) << 1);
                bf16x8 pk;
#pragma unroll
                for (int r = 0; r < 4; ++r) {
                    pk[2*r]   = (bf16)((acc[2*ip  ][j][r] + bvv) * scale);
                    pk[2*r+1] = (bf16)((acc[2*ip+1][j][r] + bvv) * scale);
                }
                *(bf16x8*)((bf16*)out +
                    ((size_t)(bb * H_ + hh) * DK_ + dd) * S_ + g0) = pk;
            }
        }
    } else {
#pragma unroll
        for (int i = 0; i < 4; ++i)
#pragma unroll
            for (int j = 0; j < 4; ++j) {
                const int nn = n0 + wc + j*16 + l16;
                const float bvv = bias[nn];
                const int mm0 = m0 + wr + i*16 + quad*4;   // 4-aligned, same b
#pragma unroll
                for (int r = 0; r < 4; ++r) {
                    const int mm = mm0 + r;
                    float v = (acc[i][j][r] + bvv) * scale;
                    if (out_mode == 1) {
                        ((float*)out)[(size_t)mm * D_ + nn] = v;
                    } else {
                        int bb = mm >> 11, ss = mm & (S_ - 1);
                        int hh = nn >> 6, dd = nn & (DK_ - 1);
                        ((bf16*)out)[((size_t)(bb * H_ + hh) * S_ + ss) * DK_ + dd] = (bf16)v;
                    }
                }
            }
    }
}

// ---------------------------------------------------------------------------
// Context + softmax denominators, fused.
// Block = 64 q-rows, one (h,b); 4 waves; each wave owns 16 q-rows over the
// full j-range (no cross-wave reduce). K and interleaved-V^T staged in 64-j
// chunks via global_load_lds into double-buffered LDS; BOTH tiles are
// [64 rows][128B] read as ds_read_b128 with the validated byte^=(row&7)<<4
// swizzle (r6 post-mortem: V's b64 reads from 64B rows were a structural
// 4-way conflict -> 25M conflict cycles; interleaved global V^T makes the PV
// fragment one 16B read, identical pattern to K). Swizzle applied on the
// per-lane GLOBAL source address (linear LDS dest, rule #21) and re-applied
// on the read side.
// Swapped QK^T: s = mfma(K,Q) puts P[j=16t+4q+r][q-col=l16] in registers; PV
// pa packing follows the interleaved k->j bijection, so P feeds PV straight
// from registers. Scores pre-scaled by 0.125*log2e -> bare v_exp2. P~
// UNNORMALIZED; row-sum L reduced with 2 shuffles; ctx written from regs.
// ---------------------------------------------------------------------------
__global__ __launch_bounds__(256)
void attn_ctx(const bf16* __restrict__ Q, const bf16* __restrict__ K,
              const bf16* __restrict__ Vt, float* __restrict__ Li,
              bf16* __restrict__ ctxOut)
{
    // 1024 blocks; bid%8 = XCD; each XCD gets 128 consecutive semantic idx
    // = 4 full (h,b) groups -> K/V (512KB each) L2-resident per XCD.
    const int bid = blockIdx.x;
    const int l   = (bid & 7) * 128 + (bid >> 3);
    const int q0  = (l & 31) * 64;
    const int h   = (l >> 5) & 15;
    const int b   = l >> 9;

    const int tid = threadIdx.x;
    const int wv = tid >> 6, lane = tid & 63, quad = lane >> 4, l16 = lane & 15;

    __shared__ bf16 Kl[2][4096];   // [buf][64 j][64 dk]  128B rows, swizzled
    __shared__ bf16 Vl[2][4096];   // [buf][64 d][64 pos] 128B rows, swizzled

    const size_t hb = (size_t)(b * H_ + h) * S_;
    const int qw = q0 + wv * 16;   // this wave's 16 q-rows

    bf16x8 qf0, qf1;
    {
        const bf16* qrow = Q + (hb + qw + l16) * DK_;
        qf0 = ld8(qrow + quad*8);
        qf1 = ld8(qrow + 32 + quad*8);
    }
    const char* Kbc = (const char*)(K  + hb * DK_);
    const char* Vbc = (const char*)(Vt + hb * DK_);  // row d at +d*S*2B

    f32x4 cacc[4];      // [db]  C[dk = db*16+quad*4+r][q = l16]
#pragma unroll
    for (int db = 0; db < 4; ++db) cacc[db] = f32x4{0.f,0.f,0.f,0.f};
    float lsum = 0.f;

    // staging constants: each wave fills rows wv*16..+16 of both tiles via
    // 2 calls x 8 rows (64 lanes x 16B = 1024B). lane -> row +(lane>>3),
    // 16B-unit (lane&7); src unit XOR'd with row&7 (= lane>>3).
    const int rbK  = wv * 16;
    const int rlan = lane >> 3;
    const int off  = (((lane & 7) ^ rlan) << 4);

#define STAGE(jc, buf)                                                        \
    do {                                                                      \
        const size_t jb = (size_t)(jc) * 64;                                  \
        g2l16(Kbc + (jb + rbK + rlan) * 128 + off,      &Kl[buf][rbK*64]);    \
        g2l16(Kbc + (jb + rbK + 8 + rlan) * 128 + off,  &Kl[buf][(rbK+8)*64]);\
        g2l16(Vbc + (size_t)(rbK + rlan) * (S_*2) + jb*2 + off,               \
              &Vl[buf][rbK*64]);                                              \
        g2l16(Vbc + (size_t)(rbK + 8 + rlan) * (S_*2) + jb*2 + off,           \
              &Vl[buf][(rbK+8)*64]);                                          \
    } while (0)

    STAGE(0, 0);
    __syncthreads();   // drains vmcnt(0): buf0 ready

    int cur = 0;
    const int sw = (l16 & 7) << 4;   // read-side XOR key (row&7 == l16&7)
    for (int jc = 0; jc < 32; ++jc) {
        STAGE((jc + 1) & 31, cur ^ 1);   // async; drained at the barrier

        const char* kb = (const char*)&Kl[cur][0];
        const char* vb = (const char*)&Vl[cur][0];

        // QK^T: 4 j-tiles of 16
        f32x4 sc[4];
#pragma unroll
        for (int t = 0; t < 4; ++t) {
            const char* kr = kb + (t*16 + l16) * 128;
            bf16x8 ka = *(const bf16x8*)(kr + ((quad*16) ^ sw));
            bf16x8 kbv = *(const bf16x8*)(kr + ((64 + quad*16) ^ sw));
            f32x4 z = {0.f,0.f,0.f,0.f};
            z = __builtin_amdgcn_mfma_f32_16x16x32_bf16(ka, qf0, z, 0, 0, 0);
            sc[t] = __builtin_amdgcn_mfma_f32_16x16x32_bf16(kbv, qf1, z, 0, 0, 0);
        }

        float ex[4][4];
#pragma unroll
        for (int t = 0; t < 4; ++t)
#pragma unroll
            for (int r = 0; r < 4; ++r)
                ex[t][r] = __builtin_amdgcn_exp2f(fminf(sc[t][r], 86.f));
#pragma unroll
        for (int t = 0; t < 4; ++t)
            lsum += (ex[t][0] + ex[t][1]) + (ex[t][2] + ex[t][3]);

        // pa packing for the interleaved V layout: pa_kc[2r+u] = P[j =
        // 32kc + 16u + 4quad + r]  (tile t = 2kc+u)
        bf16x8 pa0, pa1;
#pragma unroll
        for (int r = 0; r < 4; ++r) {
            pa0[2*r]   = (bf16)ex[0][r];
            pa0[2*r+1] = (bf16)ex[1][r];
            pa1[2*r]   = (bf16)ex[2][r];
            pa1[2*r+1] = (bf16)ex[3][r];
        }

        // PV: one b128 V read per (db, kc)
#pragma unroll
        for (int db = 0; db < 4; ++db) {
            const char* vr = vb + (db*16 + l16) * 128;
            bf16x8 va0 = *(const bf16x8*)(vr + ((quad*16) ^ sw));
            bf16x8 va1 = *(const bf16x8*)(vr + ((64 + quad*16) ^ sw));
            cacc[db] = __builtin_amdgcn_mfma_f32_16x16x32_bf16(
                va0, pa0, cacc[db], 0, 0, 0);
            cacc[db] = __builtin_amdgcn_mfma_f32_16x16x32_bf16(
                va1, pa1, cacc[db], 0, 0, 0);
        }

        __syncthreads();   // drains stage vmcnt + all waves done with cur
        cur ^= 1;
    }
#undef STAGE

    // L reduce across quads (lanes sharing l16): all lanes end with their row
    lsum += __shfl_xor(lsum, 16);
    lsum += __shfl_xor(lsum, 32);
    const float linv = 1.0f / fmaxf(lsum, 1e-30f);
    if (lane < 16) Li[hb + qw + lane] = lsum;

    // normalize + write straight from registers (8B stores, dk contiguous)
#pragma unroll
    for (int db = 0; db < 4; ++db) {
        bf16x4 pk;
#pragma unroll
        for (int r = 0; r < 4; ++r) pk[r] = (bf16)(cacc[db][r] * linv);
        *(bf16x4*)(ctxOut + (hb + qw + l16) * DK_ + db*16 + quad*4) = pk;
    }
}

// ---------------------------------------------------------------------------
// Head-mean attention weights. 1D grid, XCD-swizzled so each XCD owns one
// j-chunk (K rows for all heads L2-resident); Q streams.
// Swapped QK^T: lane holds 4 CONSECUTIVE j for its q -> f32x4 stores; linv
// hoisted per (h,q) with 1/H folded in; bare exp2 (scale folded into Q).
// ---------------------------------------------------------------------------
__global__ __launch_bounds__(256)
void attn_weights(const bf16* __restrict__ Q, const bf16* __restrict__ K,
                  const float* __restrict__ Li, float* __restrict__ attnOut)
{
    // 512 blocks: l = q-tile (32) x b (2) x j-chunk (8); each XCD gets 64
    // consecutive l = one j-chunk, both b. Bijective.
    const int bid = blockIdx.x;
    const int l   = (bid & 7) * 64 + (bid >> 3);
    const int q0  = (l & 31) * 64;
    const int b   = (l >> 5) & 1;
    const int j0  = (l >> 6) * 256;

    const int tid = threadIdx.x;
    const int wv = tid >> 6, lane = tid & 63, quad = lane >> 4, l16 = lane & 15;

    __shared__ float linv[H_][64];
#pragma unroll
    for (int i = 0; i < 4; ++i) {
        int idx = tid * 4 + i;
        int hh = idx >> 6, row = idx & 63;
        linv[hh][row] = (1.0f / H_) /
            fmaxf(Li[(size_t)(b * H_ + hh) * S_ + q0 + row], 1e-30f);
    }
    __syncthreads();

    f32x4 asum[4][4];
#pragma unroll
    for (int qt = 0; qt < 4; ++qt)
#pragma unroll
        for (int t = 0; t < 4; ++t) asum[qt][t] = f32x4{0.f,0.f,0.f,0.f};

    for (int h = 0; h < H_; ++h) {
        const size_t hb = (size_t)(b * H_ + h) * S_;
        bf16x8 qf[4][2];
        float lv[4];
#pragma unroll
        for (int qt = 0; qt < 4; ++qt) {
            const bf16* qrow = Q + (hb + q0 + qt*16 + l16) * DK_;
            qf[qt][0] = ld8(qrow + quad*8);
            qf[qt][1] = ld8(qrow + 32 + quad*8);
            lv[qt] = linv[h][qt*16 + l16];
        }
        const bf16* Kb = K + hb * DK_;
#pragma unroll
        for (int t = 0; t < 4; ++t) {
            const int jl = j0 + wv*64 + t*16;
            const bf16* krow = Kb + (size_t)(jl + l16) * DK_;
            bf16x8 kfa = ld8(krow + quad*8), kfb = ld8(krow + 32 + quad*8);
#pragma unroll
            for (int qt = 0; qt < 4; ++qt) {
                f32x4 z = {0.f,0.f,0.f,0.f};
                z = __builtin_amdgcn_mfma_f32_16x16x32_bf16(kfa, qf[qt][0], z, 0, 0, 0);
                f32x4 s = __builtin_amdgcn_mfma_f32_16x16x32_bf16(kfb, qf[qt][1], z, 0, 0, 0);
#pragma unroll
                for (int r = 0; r < 4; ++r)
                    asum[qt][t][r] += __builtin_amdgcn_exp2f(fminf(s[r], 86.f)) * lv[qt];
            }
        }
    }
#pragma unroll
    for (int qt = 0; qt < 4; ++qt)
#pragma unroll
        for (int t = 0; t < 4; ++t)
            *(f32x4*)(attnOut + ((size_t)b * S_ + q0 + qt*16 + l16) * S_
                      + j0 + wv*64 + t*16 + quad*4) = asum[qt][t];
}

// ---------------------------------------------------------------------------
extern "C" void kernel_launch(void* const* d_in, const int* in_sizes, int n_in,
                              void* d_out, int out_size, void* d_ws, size_t ws_size,
                              hipStream_t stream)
{
    (void)in_sizes; (void)n_in; (void)out_size; (void)ws_size;

    const float* query = (const float*)d_in[0];
    const float* key_t = (const float*)d_in[1];
    const float* value = (const float*)d_in[2];
    const float* Wq = (const float*)d_in[3];
    const float* bq = (const float*)d_in[4];
    const float* Wk = (const float*)d_in[5];
    const float* bk = (const float*)d_in[6];
    const float* Wv = (const float*)d_in[7];
    const float* bv = (const float*)d_in[8];
    const float* Wo = (const float*)d_in[9];
    const float* bo = (const float*)d_in[10];

    float* out     = (float*)d_out;                  // (B,S,D) fp32
    float* attnOut = out + (size_t)B_ * S_ * D_;     // (B,S,S) fp32

    const size_t nX = (size_t)B_ * S_ * D_;
    const size_t nW = (size_t)D_ * D_;

    // d_out doubles as scratch for bf16 X-converts (dead before overwrites)
    bf16* Xqb = (bf16*)d_out;
    bf16* Xkb = Xqb + nX;
    bf16* Xvb = Xkb + nX;

    // ws: Qh,Kh,VtH (25.2MB) + Wob (2.1MB) + Li (0.26MB) + [Wqb/Wkb/Wvb
    // overlaid by CtxH (8.4MB) -- W converts are dead before attn_ctx runs].
    bf16* Qh  = (bf16*)d_ws;
    bf16* Kh  = Qh + nX;
    bf16* VtH = Kh + nX;                 // V^T (B,H,DK,S), pair-interleaved
    bf16* Wob = VtH + nX;
    float* Li = (float*)(Wob + nW);
    bf16* Wqb = (bf16*)(Li + (size_t)B_ * H_ * S_);
    bf16* Wkb = Wqb + nW;
    bf16* Wvb = Wkb + nW;
    bf16* CtxH = Wqb;                                // overlays dead W converts

    cvt_all<<<8192, 256, 0, stream>>>(query, key_t, value, Wq, Wk, Wv, Wo,
                                      Xqb, Xkb, Xvb, Wqb, Wkb, Wvb, Wob);
    dim3 gg(M_/128, D_/128);
    // Q pre-scaled by 1/sqrt(DK) * log2(e): softmax scale + exp->exp2 fold
    gemm128<<<gg, 256, 0, stream>>>(Xqb, Wqb, bq, Qh, 0, 0, 0.18033688011112042f);
    gemm128<<<gg, 256, 0, stream>>>(Xkb, Wkb, bk, Kh, 0, 0, 1.0f);
    gemm128<<<gg, 256, 0, stream>>>(Xvb, Wvb, bv, VtH, 0, 2, 1.0f);   // V^T
    attn_ctx    <<<1024, 256, 0, stream>>>(Qh, Kh, VtH, Li, CtxH);
    attn_weights<<<512, 256, 0, stream>>>(Qh, Kh, Li, attnOut);
    gemm128<<<gg, 256, 0, stream>>>(CtxH, Wob, bo, out, 1, 1, 1.0f);
}